// Round 2
// baseline (1053.668 us; speedup 1.0000x reference)
//
#include <hip/hip_runtime.h>
#include <math.h>

// RNN_197568496340: 6-layer ReLU RNN (T=1024,B=2048,IN=2,H=20) + FC(20->2) + log_softmax.
//
// R2: persistent pipelined blocks, re-tiled for balance.
//  - 512 blocks (2/CU), CB=4 batch elems each, 2 waves (128 thr).
//  - Work pool per wall-step: 24 (layer,batch) pairs x 20 neurons.
//    5 lanes per pair, 4 neurons per lane (exact 20 -> no FMA padding).
//  - Layer 0 made uniform with layers 1..5: x_t staged into LDS slot 0 by
//    4 writer lanes (3-step global prefetch); Wih0 zero-padded to 20 wide.
//  - Head (FC + log_softmax) on 4 lanes of wave 1, weights overlaid into the
//    same register arrays as layer lanes to cap VGPR pressure.
//  - LDS ring: slot s (0=x, 1+l=layer l out), double-buffered by step parity,
//    slot stride padded +8 words to spread banks. One barrier per step.

#define TT 1024
#define BB 2048
#define HH 20
#define LL 6
#define CB 4
#define NBLK (BB / CB)          // 512 blocks -> 2 per CU
#define NTHR 128                // 2 waves
#define NSTEPS (TT + LL)        // 1030: head (t = s-6) last active at s = 1029
#define SS 168                  // slot stride in floats (2*PS + 8 pad words)
#define PS 80                   // parity stride = CB*HH
#define ASIZE (6 * SS + 2 * PS) // 1168 floats = 4672 B

__global__ __launch_bounds__(NTHR, 2)
void rnn_fused(const float* __restrict__ x,
               const float* __restrict__ Wih0,   // [20][2]
               const float* __restrict__ Wih,    // [5][20][20]
               const float* __restrict__ Whh,    // [6][20][20]
               const float* __restrict__ bih,    // [6][20]
               const float* __restrict__ bhh,    // [6][20]
               const float* __restrict__ fcw,    // [2][20]
               const float* __restrict__ fcb,    // [2]
               float* __restrict__ out)          // [1024][2048][2]
{
    __shared__ __align__(16) float As[ASIZE];

    const int tid = threadIdx.x;
    const int bg0 = blockIdx.x * CB;

    const bool is_layer = tid < 120;
    const bool is_head  = (tid >= 120) && (tid < 124);
    // tid 124..127: x-writer lanes

    int l = 0, b = 0, j0 = 0;
    if (is_layer) {
        const int p = tid / 5;      // pair 0..23
        const int g = tid % 5;      // neuron group 0..4
        l = p >> 2;                 // 0..5
        b = p & 3;                  // 0..3
        j0 = g * 4;                 // 0,4,8,12,16
    } else if (is_head) {
        b = tid - 120;
    } else {
        b = tid - 124;
    }

    // register-resident weights (head overlays fc weights into rows 0,1)
    float whw[4][HH];
    float wiw[4][HH];
    float bias[4];
#pragma unroll
    for (int r = 0; r < 4; ++r) {
        bias[r] = 0.f;
#pragma unroll
        for (int k = 0; k < HH; ++k) { whw[r][k] = 0.f; wiw[r][k] = 0.f; }
    }

    if (is_layer) {
#pragma unroll
        for (int r = 0; r < 4; ++r) {
            const int j = j0 + r;
            bias[r] = bih[l * HH + j] + bhh[l * HH + j];
            const float4* wr = (const float4*)&Whh[(l * HH + j) * HH];
#pragma unroll
            for (int q = 0; q < 5; ++q) {
                float4 t4 = wr[q];
                whw[r][4*q+0] = t4.x; whw[r][4*q+1] = t4.y;
                whw[r][4*q+2] = t4.z; whw[r][4*q+3] = t4.w;
            }
            if (l == 0) {
                wiw[r][0] = Wih0[j * 2 + 0];
                wiw[r][1] = Wih0[j * 2 + 1];
                // rest stays 0 (x slot rows are zero beyond the first 2 floats)
            } else {
                const float4* wi = (const float4*)&Wih[((l - 1) * HH + j) * HH];
#pragma unroll
                for (int q = 0; q < 5; ++q) {
                    float4 t4 = wi[q];
                    wiw[r][4*q+0] = t4.x; wiw[r][4*q+1] = t4.y;
                    wiw[r][4*q+2] = t4.z; wiw[r][4*q+3] = t4.w;
                }
            }
        }
    } else if (is_head) {
#pragma unroll
        for (int k = 0; k < HH; ++k) {
            whw[0][k] = fcw[k];
            whw[1][k] = fcw[HH + k];
        }
        bias[0] = fcb[0];
        bias[1] = fcb[1];
    }

    // zero LDS (h(-1)=0 everywhere; x-slot pad columns stay 0 forever)
    for (int i = tid; i < ASIZE; i += NTHR) As[i] = 0.f;
    __syncthreads();

    // x staging prologue: write x[0] into slot0 parity 1 (read at s=0),
    // prefetch x[1], x[2] into registers.
    const float2* xp = (const float2*)x;
    float2 xv = make_float2(0.f, 0.f);
    float2 xn = make_float2(0.f, 0.f);
    if (tid >= 124) {
        float2 x0 = xp[bg0 + b];
        *(float2*)&As[PS + b * HH] = x0;
        xv = xp[(size_t)1 * BB + bg0 + b];
        xn = xp[(size_t)2 * BB + bg0 + b];
    }
    __syncthreads();

    // per-lane LDS bases (word offsets, parity added per step)
    const int hoff = is_layer ? ((1 + l) * SS + b * HH)   // own layer slot
                              : (6 * SS + b * HH);        // head: layer-5 slot
    const int ioff = l * SS + b * HH;                     // input slot (layer: l; l=0 -> x slot)

    float2* const op = (float2*)out;

    for (int s = 0; s < NSTEPS; ++s) {
        const int rp = ((s + 1) & 1) * PS;   // read parity
        const int wp = (s & 1) * PS;         // write parity

        if (is_layer) {
            const int t = s - l;
            if (t >= 0 && t < TT) {
                float hv[HH], iv[HH];
                const float4* hb = (const float4*)&As[hoff + rp];
                const float4* ib = (const float4*)&As[ioff + rp];
#pragma unroll
                for (int q = 0; q < 5; ++q) {
                    float4 h4 = hb[q];
                    hv[4*q+0] = h4.x; hv[4*q+1] = h4.y; hv[4*q+2] = h4.z; hv[4*q+3] = h4.w;
                }
#pragma unroll
                for (int q = 0; q < 5; ++q) {
                    float4 i4 = ib[q];
                    iv[4*q+0] = i4.x; iv[4*q+1] = i4.y; iv[4*q+2] = i4.z; iv[4*q+3] = i4.w;
                }
                float a0 = bias[0], a1 = bias[1], a2 = bias[2], a3 = bias[3];
#pragma unroll
                for (int k = 0; k < HH; ++k) {
                    a0 = fmaf(whw[0][k], hv[k], a0);
                    a1 = fmaf(whw[1][k], hv[k], a1);
                    a2 = fmaf(whw[2][k], hv[k], a2);
                    a3 = fmaf(whw[3][k], hv[k], a3);
                    a0 = fmaf(wiw[0][k], iv[k], a0);
                    a1 = fmaf(wiw[1][k], iv[k], a1);
                    a2 = fmaf(wiw[2][k], iv[k], a2);
                    a3 = fmaf(wiw[3][k], iv[k], a3);
                }
                float4 o;
                o.x = fmaxf(a0, 0.f);
                o.y = fmaxf(a1, 0.f);
                o.z = fmaxf(a2, 0.f);
                o.w = fmaxf(a3, 0.f);
                *(float4*)&As[hoff + wp + j0] = o;   // one b128 write
            }
        } else if (is_head) {
            const int t = s - LL;
            if (t >= 0) {   // t <= 1023 guaranteed by NSTEPS
                float hv[HH];
                const float4* hb = (const float4*)&As[hoff + rp];
#pragma unroll
                for (int q = 0; q < 5; ++q) {
                    float4 h4 = hb[q];
                    hv[4*q+0] = h4.x; hv[4*q+1] = h4.y; hv[4*q+2] = h4.z; hv[4*q+3] = h4.w;
                }
                float l0 = bias[0], l1 = bias[1];
#pragma unroll
                for (int k = 0; k < HH; ++k) {
                    l0 = fmaf(whw[0][k], hv[k], l0);
                    l1 = fmaf(whw[1][k], hv[k], l1);
                }
                const float mx  = fmaxf(l0, l1);
                const float lse = mx + __logf(__expf(l0 - mx) + __expf(l1 - mx));
                float2 o2;
                o2.x = l0 - lse;
                o2.y = l1 - lse;
                op[(size_t)t * BB + bg0 + b] = o2;
            }
        } else {
            // x writer: at step s publish x[s+1] (read by layer 0 at s+1)
            if (s + 1 < TT) *(float2*)&As[wp + b * HH] = xv;
            xv = xn;
            if (s + 3 < TT) xn = xp[(size_t)(s + 3) * BB + bg0 + b];
        }
        __syncthreads();
    }
}

extern "C" void kernel_launch(void* const* d_in, const int* in_sizes, int n_in,
                              void* d_out, int out_size, void* d_ws, size_t ws_size,
                              hipStream_t stream) {
    const float* x    = (const float*)d_in[0];
    const float* Wih0 = (const float*)d_in[1];
    const float* Wih  = (const float*)d_in[2];
    const float* Whh  = (const float*)d_in[3];
    const float* bih  = (const float*)d_in[4];
    const float* bhh  = (const float*)d_in[5];
    const float* fcw  = (const float*)d_in[6];
    const float* fcb  = (const float*)d_in[7];
    float* out = (float*)d_out;

    rnn_fused<<<dim3(NBLK), dim3(NTHR), 0, stream>>>(
        x, Wih0, Wih, Whh, bih, bhh, fcw, fcb, out);
}

// Round 4
// 579.974 us; speedup vs baseline: 1.8168x; 1.8168x over previous
//
#include <hip/hip_runtime.h>
#include <math.h>

// RNN_197568496340: 6-layer ReLU RNN (T=1024,B=2048,IN=2,H=20) + FC(20->2) + log_softmax.
//
// R4 = R3 with the macro-parameter/.w token collision fixed (param renamed Wt).
//
// Design: single-wave persistent blocks, diagonal layer schedule, zero barriers.
//  - 2048 blocks x 64 threads (1 wave). Block b owns batch element b.
//  - Lanes 0..59: (layer l = lane/10, neuron pair j = 2*(lane%10)). At wall
//    step s, layer l computes t = s-l. All inputs (own h[t-1], layer l-1's
//    output at t) were produced at step s-1 -> everything in a step is
//    independent; wave-internal LDS ordering (DS ops are in-order per wave)
//    replaces __syncthreads, so NO vmcnt drain per step (R1/R2's hidden cost).
//  - Lane 60: FC head as pseudo-layer (whw=fcw rows, wiw=0, no relu) +
//    log_softmax + store. Lanes 61..63: x prefetch ring, period 3 -> each
//    global load has ~3 steps of latency slack before its LDS write.
//  - Per-lane weights = 80 floats, register-resident (~160 VGPR < 256 cap;
//    R2's 220-float/lane demand spilled to scratch and re-fetched every step).
//  - LDS: 7 slots (0=x, 1+l=layer l out) x 40-word stride, double-buffered by
//    step parity (manual 2x unroll makes parity static). All ds_read_b128
//    address groups are <=2-way bank-aliased (free on gfx950, m136).

#define TT 1024
#define BB 2048
#define HH 20
#define LL 6
#define SLOTW 40
#define BUFW  (7 * SLOTW + 8)   // 288 words per parity buffer
#define NSTEPS (TT + LL)        // 1030 (even, so 2x-unrolled loop is exact)

#define FMA4(acc, Wt, c, v4)                                          \
    acc = fmaf(Wt[4*(c)+0], v4.x, acc);                               \
    acc = fmaf(Wt[4*(c)+1], v4.y, acc);                               \
    acc = fmaf(Wt[4*(c)+2], v4.z, acc);                               \
    acc = fmaf(Wt[4*(c)+3], v4.w, acc);

__global__ __launch_bounds__(64, 2)
void rnn_fused(const float* __restrict__ x,      // [1024][2048][2]
               const float* __restrict__ Wih0,   // [20][2]
               const float* __restrict__ Wih,    // [5][20][20]
               const float* __restrict__ Whh,    // [6][20][20]
               const float* __restrict__ bih,    // [6][20]
               const float* __restrict__ bhh,    // [6][20]
               const float* __restrict__ fcw,    // [2][20]
               const float* __restrict__ fcb,    // [2]
               float* __restrict__ out)          // [1024][2048][2]
{
    __shared__ __align__(16) float As[2 * BUFW];   // 2304 B

    const int lane = threadIdx.x;
    const int b    = blockIdx.x;
    const bool is_layer = lane < 60;
    const int l  = is_layer ? (lane / 10) : 0;
    const int gj = is_layer ? (lane % 10) : 0;
    const int j  = 2 * gj;

    // ---- register-resident weights (80 floats/lane) ----
    float wh0[HH], wh1[HH], wi0[HH], wi1[HH];
    float bs0, bs1;

    if (is_layer) {
        const float4* r0 = (const float4*)&Whh[(l * HH + j) * HH];
        const float4* r1 = (const float4*)&Whh[(l * HH + j + 1) * HH];
#pragma unroll
        for (int q = 0; q < 5; ++q) {
            float4 t0 = r0[q], t1 = r1[q];
            wh0[4*q+0] = t0.x; wh0[4*q+1] = t0.y; wh0[4*q+2] = t0.z; wh0[4*q+3] = t0.w;
            wh1[4*q+0] = t1.x; wh1[4*q+1] = t1.y; wh1[4*q+2] = t1.z; wh1[4*q+3] = t1.w;
        }
        bs0 = bih[l * HH + j]     + bhh[l * HH + j];
        bs1 = bih[l * HH + j + 1] + bhh[l * HH + j + 1];
        if (l == 0) {
#pragma unroll
            for (int k = 0; k < HH; ++k) { wi0[k] = 0.f; wi1[k] = 0.f; }
            wi0[0] = Wih0[j * 2 + 0];       wi0[1] = Wih0[j * 2 + 1];
            wi1[0] = Wih0[(j + 1) * 2 + 0]; wi1[1] = Wih0[(j + 1) * 2 + 1];
        } else {
            const float4* q0 = (const float4*)&Wih[((l - 1) * HH + j) * HH];
            const float4* q1 = (const float4*)&Wih[((l - 1) * HH + j + 1) * HH];
#pragma unroll
            for (int q = 0; q < 5; ++q) {
                float4 t0 = q0[q], t1 = q1[q];
                wi0[4*q+0] = t0.x; wi0[4*q+1] = t0.y; wi0[4*q+2] = t0.z; wi0[4*q+3] = t0.w;
                wi1[4*q+0] = t1.x; wi1[4*q+1] = t1.y; wi1[4*q+2] = t1.z; wi1[4*q+3] = t1.w;
            }
        }
    } else {
        // head pseudo-layer: whw = fc rows, wiw = 0 (reads slot 0, contributes 0)
#pragma unroll
        for (int k = 0; k < HH; ++k) {
            wh0[k] = fcw[k];
            wh1[k] = fcw[HH + k];
            wi0[k] = 0.f; wi1[k] = 0.f;
        }
        bs0 = fcb[0]; bs1 = fcb[1];
    }

    // ---- LDS init: h(-1)=0 for all layers, both parities; x[0] into buf0 ----
    for (int i = lane; i < 2 * BUFW; i += 64) As[i] = 0.f;
    asm volatile("" ::: "memory");

    const float2* xp = (const float2*)x;
    float2 xh = make_float2(0.f, 0.f);
    if (lane == 61) *(float2*)&As[0] = xp[b];                       // x[0] -> buf0 slot0
    if (lane >= 61) xh = xp[(size_t)(lane - 60) * BB + b];          // hold x[1],x[2],x[3]
    asm volatile("s_waitcnt lgkmcnt(0)" ::: "memory");

    // per-lane LDS word offsets (head reads slot 6 = same addrs as layer 5 -> broadcast)
    const int hoff = (is_layer ? (l + 1) : 6) * SLOTW;
    const int ioff = (is_layer ? l : 0) * SLOTW;
    const int woff = (l + 1) * SLOTW + j;
    float2* const op = (float2*)out;

    auto step = [&](int s, const float* rb, float* wb) {
        const float4* hp = (const float4*)(rb + hoff);
        const float4* ip = (const float4*)(rb + ioff);
        float4 h0 = hp[0], h1 = hp[1], h2 = hp[2], h3 = hp[3], h4 = hp[4];
        float4 i0 = ip[0], i1 = ip[1], i2 = ip[2], i3 = ip[3], i4 = ip[4];

        float ah0 = bs0, ah1 = bs1, ai0 = 0.f, ai1 = 0.f;
        FMA4(ah0, wh0, 0, h0) FMA4(ah0, wh0, 1, h1) FMA4(ah0, wh0, 2, h2)
        FMA4(ah0, wh0, 3, h3) FMA4(ah0, wh0, 4, h4)
        FMA4(ah1, wh1, 0, h0) FMA4(ah1, wh1, 1, h1) FMA4(ah1, wh1, 2, h2)
        FMA4(ah1, wh1, 3, h3) FMA4(ah1, wh1, 4, h4)
        FMA4(ai0, wi0, 0, i0) FMA4(ai0, wi0, 1, i1) FMA4(ai0, wi0, 2, i2)
        FMA4(ai0, wi0, 3, i3) FMA4(ai0, wi0, 4, i4)
        FMA4(ai1, wi1, 0, i0) FMA4(ai1, wi1, 1, i1) FMA4(ai1, wi1, 2, i2)
        FMA4(ai1, wi1, 3, i3) FMA4(ai1, wi1, 4, i4)
        const float a0 = ah0 + ai0;
        const float a1 = ah1 + ai1;

        if (is_layer) {
            if ((unsigned)(s - l) < TT) {                 // t in [0,1023]
                float2 r;
                r.x = fmaxf(a0, 0.f);
                r.y = fmaxf(a1, 0.f);
                *(float2*)(wb + woff) = r;
            }
        } else if (lane == 60) {
            if (s >= LL) {
                const float mx  = fmaxf(a0, a1);
                const float lse = mx + __logf(__expf(a0 - mx) + __expf(a1 - mx));
                op[(size_t)(s - LL) * BB + b] = make_float2(a0 - lse, a1 - lse);
            }
        } else {
            // x ring: lane d = lane-61 acts when s % 3 == d; holds x[s+1] then
            // prefetches x[s+4] (consumed 3 steps later -> latency hidden)
            if (lane - 61 == s % 3) {
                if (s + 1 < TT) *(float2*)(wb + 0) = xh;
                int tl = s + 4; if (tl > TT - 1) tl = TT - 1;
                xh = xp[(size_t)tl * BB + b];
            }
        }
        // wave-internal ordering only: DS ops are in-order per wave; this
        // stops the compiler from sinking writes past next step's reads and
        // waits out the (cheap) LDS write latency. No vmcnt drain.
        asm volatile("s_waitcnt lgkmcnt(0)" ::: "memory");
    };

    float* const buf0 = As;
    float* const buf1 = As + BUFW;
    for (int s = 0; s < NSTEPS; s += 2) {
        step(s,     buf0, buf1);
        step(s + 1, buf1, buf0);
    }
}

extern "C" void kernel_launch(void* const* d_in, const int* in_sizes, int n_in,
                              void* d_out, int out_size, void* d_ws, size_t ws_size,
                              hipStream_t stream) {
    const float* x    = (const float*)d_in[0];
    const float* Wih0 = (const float*)d_in[1];
    const float* Wih  = (const float*)d_in[2];
    const float* Whh  = (const float*)d_in[3];
    const float* bih  = (const float*)d_in[4];
    const float* bhh  = (const float*)d_in[5];
    const float* fcw  = (const float*)d_in[6];
    const float* fcb  = (const float*)d_in[7];
    float* out = (float*)d_out;

    rnn_fused<<<dim3(BB), dim3(64), 0, stream>>>(
        x, Wih0, Wih, Whh, bih, bhh, fcw, fcb, out);
}

// Round 5
// 568.732 us; speedup vs baseline: 1.8527x; 1.0198x over previous
//
#include <hip/hip_runtime.h>
#include <math.h>

// RNN_197568496340: 6-layer ReLU RNN (T=1024,B=2048,IN=2,H=20) + FC(20->2) + log_softmax.
//
// R5: R4 skeleton (2048 single-wave persistent blocks, diagonal layer schedule,
// zero barriers) with the register-allocation failure fixed:
//  - R4 showed VGPR_Count=64: the 80 weight floats/lane were AGPR/scratch-parked,
//    costing ~+96 VALU insts/step (moves) + 49MB FETCH leak. Fix: branch-free
//    uniform init from a staged, padded weight image in d_ws; weights held as
//    float4 whA/whB/wiA/wiB[5] (SROA-trivial); activations streamed.
//  - Head = pseudo-layer l=6: input side reads slot 6 (h5) with fcw weights,
//    recurrent side reads slot 7 (all zeros, never written) -> exact 0.
//  - No "memory"-clobber asm in the loop (R4 suspect); LDS ordering is per-wave
//    in-order + may-alias deps; sched_barrier(0) as a free scheduling fence.
//  - XCD swizzle of batch index so adjacent b share an XCD L2 (merge 8B stores).

#define TT 1024
#define BB 2048
#define HH 20
#define LL 6
#define SLOTW 40
#define BUFW  (8 * SLOTW)       // 320 words/parity: slots 0=x,1..6=layer outs,7=zeros
#define NSTEPS (TT + LL)        // 1030 (even)

// ws layout (floats)
#define WS_WI   0               // padded Wih: [6][20][20] (layer0 = Wih0 zero-padded)
#define WS_BIAS 2400            // BiasTab: [61][2]  (role 60 = fcb)

__global__ void stage_ws(const float* __restrict__ Wih0,
                         const float* __restrict__ Wih,
                         const float* __restrict__ bih,
                         const float* __restrict__ bhh,
                         const float* __restrict__ fcb,
                         float* __restrict__ ws) {
    const int i = threadIdx.x + blockIdx.x * blockDim.x;
    if (i < 2400) {
        const int l = i / 400, r = i % 400, j = r / 20, k = r % 20;
        float v;
        if (l == 0) v = (k < 2) ? Wih0[j * 2 + k] : 0.f;
        else        v = Wih[(l - 1) * 400 + r];
        ws[WS_WI + i] = v;
    }
    if (i < 122) {
        const int role = i >> 1, c = i & 1;
        float v;
        if (role < 60) {
            const int l = role / 10, j = 2 * (role % 10) + c;
            v = bih[l * HH + j] + bhh[l * HH + j];
        } else {
            v = fcb[c];
        }
        ws[WS_BIAS + i] = v;
    }
}

__global__ __launch_bounds__(64, 2)
void rnn_fused(const float* __restrict__ x,      // [1024][2048][2]
               const float* __restrict__ Whh,    // [6][20][20]
               const float* __restrict__ fcw,    // [2][20]
               const float* __restrict__ ws,     // staged WI_pad + BiasTab
               float* __restrict__ out)          // [1024][2048][2]
{
    __shared__ __align__(16) float As[2 * BUFW];   // 2560 B

    const int lane = threadIdx.x;
    // XCD swizzle: consecutive b on the same XCD -> L2 write combining
    const int b = ((blockIdx.x & 7) << 8) | (blockIdx.x >> 3);

    const int  role = (lane < 60) ? lane : 60;
    const int  l    = role / 10;            // 0..6 (6 = head pseudo-layer)
    const int  j    = 2 * (role % 10);      // 0 for head
    const bool head = (role == 60);

    // ---- branch-free uniform weight init (pointers differ, code identical) ----
    const float4* pwh = (const float4*)(head ? Whh : (Whh + (l * HH + j) * HH));
    const float4* pwi = (const float4*)(head ? fcw : (ws + WS_WI + (l * HH + j) * HH));
    const float2  bt  = *(const float2*)(ws + WS_BIAS + 2 * role);

    float4 whA[5], whB[5], wiA[5], wiB[5];
#pragma unroll
    for (int q = 0; q < 5; ++q) {
        whA[q] = pwh[q];
        whB[q] = pwh[5 + q];
        wiA[q] = pwi[q];
        wiB[q] = pwi[5 + q];
    }

    // ---- LDS init: everything zero (h(-1)=0, zero-slot stays zero forever) ----
    for (int i = lane; i < 2 * BUFW; i += 64) As[i] = 0.f;

    // x staging: x[0] -> buf0 slot0; ring lanes 61..63 hold x[1..3]
    const float2* xp = (const float2*)x;
    float2 xh = make_float2(0.f, 0.f);
    if (lane == 61) *(float2*)&As[0] = xp[b];
    if (lane >= 61) xh = xp[(size_t)(lane - 60) * BB + b];

    // per-lane LDS word offsets (uniform formula, head included)
    const int ioff = l * SLOTW;             // input slot (head: slot 6 = h5)
    const int hoff = (l + 1) * SLOTW;       // recurrent slot (head: slot 7 = zeros)
    float2* const op = (float2*)out;

    auto step = [&](int s, const float* rb, float* wb) {
        const float4* hp = (const float4*)(rb + hoff);
        const float4* ip = (const float4*)(rb + ioff);

        float ah0 = 0.f, ah1 = 0.f;
        float ai0 = bt.x, ai1 = bt.y;
#pragma unroll
        for (int q = 0; q < 5; ++q) {
            const float4 h4 = hp[q];
            const float4 i4 = ip[q];
            ah0 = fmaf(whA[q].x, h4.x, ah0); ah0 = fmaf(whA[q].y, h4.y, ah0);
            ah0 = fmaf(whA[q].z, h4.z, ah0); ah0 = fmaf(whA[q].w, h4.w, ah0);
            ah1 = fmaf(whB[q].x, h4.x, ah1); ah1 = fmaf(whB[q].y, h4.y, ah1);
            ah1 = fmaf(whB[q].z, h4.z, ah1); ah1 = fmaf(whB[q].w, h4.w, ah1);
            ai0 = fmaf(wiA[q].x, i4.x, ai0); ai0 = fmaf(wiA[q].y, i4.y, ai0);
            ai0 = fmaf(wiA[q].z, i4.z, ai0); ai0 = fmaf(wiA[q].w, i4.w, ai0);
            ai1 = fmaf(wiB[q].x, i4.x, ai1); ai1 = fmaf(wiB[q].y, i4.y, ai1);
            ai1 = fmaf(wiB[q].z, i4.z, ai1); ai1 = fmaf(wiB[q].w, i4.w, ai1);
        }
        const float a0 = ah0 + ai0;
        const float a1 = ah1 + ai1;

        if (role < 60) {
            if ((unsigned)(s - l) < TT) {                  // t in [0,1023]
                float2 r;
                r.x = fmaxf(a0, 0.f);
                r.y = fmaxf(a1, 0.f);
                *(float2*)(wb + hoff + j) = r;
            }
        } else if (lane == 60) {
            if (s >= LL) {
                const float mx  = fmaxf(a0, a1);
                const float lse = mx + __logf(__expf(a0 - mx) + __expf(a1 - mx));
                op[(size_t)(s - LL) * BB + b] = make_float2(a0 - lse, a1 - lse);
            }
        } else {
            // x ring: lane d = lane-61 acts when s % 3 == d; publishes x[s+1],
            // then prefetches x[s+4] (3 steps of latency slack)
            if (lane - 61 == s % 3) {
                if (s + 1 < TT) *(float2*)(wb + 0) = xh;
                int tl = s + 4; if (tl > TT - 1) tl = TT - 1;
                xh = xp[(size_t)tl * BB + b];
            }
        }
        __builtin_amdgcn_sched_barrier(0);   // scheduling fence only (no mem clobber)
    };

    float* const buf0 = As;
    float* const buf1 = As + BUFW;
    for (int s = 0; s < NSTEPS; s += 2) {
        step(s,     buf0, buf1);
        step(s + 1, buf1, buf0);
    }
}

extern "C" void kernel_launch(void* const* d_in, const int* in_sizes, int n_in,
                              void* d_out, int out_size, void* d_ws, size_t ws_size,
                              hipStream_t stream) {
    const float* x    = (const float*)d_in[0];
    const float* Wih0 = (const float*)d_in[1];
    const float* Wih  = (const float*)d_in[2];
    const float* Whh  = (const float*)d_in[3];
    const float* bih  = (const float*)d_in[4];
    const float* bhh  = (const float*)d_in[5];
    const float* fcw  = (const float*)d_in[6];
    const float* fcb  = (const float*)d_in[7];
    float* out = (float*)d_out;
    float* ws  = (float*)d_ws;

    stage_ws<<<dim3(3), dim3(1024), 0, stream>>>(Wih0, Wih, bih, bhh, fcb, ws);
    rnn_fused<<<dim3(BB), dim3(64), 0, stream>>>(x, Whh, fcw, ws, out);
}